// Round 1
// baseline (118.817 us; speedup 1.0000x reference)
//
#include <hip/hip_runtime.h>

// Problem constants (from the reference)
#define B_DIM 16384
#define C_DIM 10000
#define C_VEC (C_DIM / 4)   // 2500 float4 per row (40000 B, 16B-aligned rows)
#define A_CONST (-4.0f)

// Combine two online-softmax states (m1,s1),(m2,s2)
__device__ inline void combine(float& m, float& s, float mo, float so) {
    float mn = fmaxf(m, mo);
    s = s * __expf(m - mn) + so * __expf(mo - mn);
    m = mn;
}

__global__ __launch_bounds__(256) void ces_row_kernel(
        const float* __restrict__ x,
        const int* __restrict__ tgt,
        float* __restrict__ row_out) {
    const int row = blockIdx.x;
    const float* xr = x + (size_t)row * C_DIM;
    const float4* xv = reinterpret_cast<const float4*>(xr);
    const int tid = threadIdx.x;

    // Online max/sum over this thread's strided slice. Every thread gets
    // >= 9 float4s (2500/256), so m is always finite after the loop.
    float m = -3.0e38f;   // finite sentinel: exp(m - mn) underflows to 0, no NaN
    float s = 0.0f;
    for (int j = tid; j < C_VEC; j += 256) {
        float4 v = xv[j];
        float m4 = fmaxf(fmaxf(v.x, v.y), fmaxf(v.z, v.w));
        float mn = fmaxf(m, m4);
        s = s * __expf(m - mn)
          + __expf(v.x - mn) + __expf(v.y - mn)
          + __expf(v.z - mn) + __expf(v.w - mn);
        m = mn;
    }

    // Wave (64-lane) butterfly combine
    #pragma unroll
    for (int off = 32; off >= 1; off >>= 1) {
        float mo = __shfl_xor(m, off);
        float so = __shfl_xor(s, off);
        combine(m, s, mo, so);
    }

    // Cross-wave combine via LDS (4 waves / block)
    __shared__ float sm[4], ss[4];
    const int wave = tid >> 6;
    if ((tid & 63) == 0) { sm[wave] = m; ss[wave] = s; }
    __syncthreads();

    if (tid == 0) {
        m = sm[0]; s = ss[0];
        #pragma unroll
        for (int w = 1; w < 4; ++w) combine(m, s, sm[w], ss[w]);

        const int t = tgt[row];
        const float xt = xr[t];               // L2-hot gather
        const float logs = __logf(s);
        const float neg_logp_t = m + logs - xt;      // -log_softmax at target
        const float p_t = __expf(xt - m) / s;        // softmax at target
        // a*ce + b*ces contributions, a=b=1:
        //   (1/B)*neg_logp_t + (A/B)*(p_t - rowsum_p), rowsum_p == 1 to fp32
        row_out[row] = (1.0f / B_DIM) * neg_logp_t
                     + (A_CONST / B_DIM) * (p_t - 1.0f);
    }
}

__global__ __launch_bounds__(1024) void ces_reduce_kernel(
        const float* __restrict__ row_out,
        float* __restrict__ out) {
    __shared__ float sm[16];
    const int tid = threadIdx.x;
    float acc = 0.0f;
    #pragma unroll
    for (int j = tid; j < B_DIM; j += 1024) acc += row_out[j];
    #pragma unroll
    for (int off = 32; off >= 1; off >>= 1) acc += __shfl_xor(acc, off);
    if ((tid & 63) == 0) sm[tid >> 6] = acc;
    __syncthreads();
    if (tid == 0) {
        float r = 0.0f;
        #pragma unroll
        for (int w = 0; w < 16; ++w) r += sm[w];
        out[0] = r;
    }
}

extern "C" void kernel_launch(void* const* d_in, const int* in_sizes, int n_in,
                              void* d_out, int out_size, void* d_ws, size_t ws_size,
                              hipStream_t stream) {
    const float* outputs = (const float*)d_in[0];   // [B, C] fp32
    const int*   targets = (const int*)d_in[1];     // [B] int
    float* row_out = (float*)d_ws;                  // B floats scratch
    float* out = (float*)d_out;                     // scalar

    ces_row_kernel<<<B_DIM, 256, 0, stream>>>(outputs, targets, row_out);
    ces_reduce_kernel<<<1, 1024, 0, stream>>>(row_out, out);
}